// Round 8
// baseline (8148.438 us; speedup 1.0000x reference)
//
#include <hip/hip_runtime.h>
#include <hip/hip_bf16.h>

#define B 64
#define KDIM 196
#define H 512
#define V 10000
#define TSTEPS 30
#define VP 10240       // padded V: 64 strips * 160
#define NVC 40         // VP/256 chunks (base finish)
#define NSLOT 8
#define SLOTSTRIDE 16  // u64 per b -> 128B
#define NBLK 512
#define NT 256

typedef unsigned long long u64;
typedef unsigned int u32;

__device__ __forceinline__ u64 pack_vi(float v, int idx) {
    u32 kb = __float_as_uint(v);
    kb = (kb & 0x80000000u) ? ~kb : (kb | 0x80000000u);
    return ((u64)kb << 32) | (u32)(~(u32)idx);
}
__device__ __forceinline__ u32 best_idx_of_slots(const u64* __restrict__ slots, int b) {
    u64 best = slots[b * SLOTSTRIDE];
#pragma unroll
    for (int s = 1; s < NSLOT; ++s) { u64 v = slots[b * SLOTSTRIDE + s]; if (v > best) best = v; }
    return ~(u32)best;
}

// device-wide barrier: all NBLK blocks co-resident (cap 3/CU*256 > 512)
__device__ __forceinline__ void gbar(u32* cnt, u32* gen, u32& mygen) {
    __syncthreads();
    if (threadIdx.x == 0) {
        __threadfence();   // release our writes (agent scope, cross-XCD)
        u32 old = __hip_atomic_fetch_add(cnt, 1u, __ATOMIC_ACQ_REL, __HIP_MEMORY_SCOPE_AGENT);
        if (old == (u32)NBLK - 1) {
            __hip_atomic_store(cnt, 0u, __ATOMIC_RELAXED, __HIP_MEMORY_SCOPE_AGENT);
            __hip_atomic_fetch_add(gen, 1u, __ATOMIC_RELEASE, __HIP_MEMORY_SCOPE_AGENT);
        } else {
            while (__hip_atomic_load(gen, __ATOMIC_RELAXED, __HIP_MEMORY_SCOPE_AGENT) <= mygen)
                __builtin_amdgcn_s_sleep(2);
            __threadfence();   // acquire: invalidate L1/L2 once after release observed
        }
    }
    ++mygen;
    __syncthreads();
}

// ---------------- precompute kernels (unchanged from r7) ----------------

__global__ void k_transpose_fc(const float* __restrict__ fcw, float* __restrict__ dst, int coloff) {
    __shared__ float tile[32][33];
    int v0 = blockIdx.x * 32, i0 = blockIdx.y * 32;
    int tx = threadIdx.x, ty = threadIdx.y;
#pragma unroll
    for (int r = 0; r < 32; r += 8) {
        int v = v0 + ty + r; int i = i0 + tx;
        tile[ty + r][tx] = (v < V) ? fcw[(size_t)v * 1024 + coloff + i] : 0.f;
    }
    __syncthreads();
#pragma unroll
    for (int r = 0; r < 32; r += 8) {
        int i = i0 + ty + r; int v = v0 + tx;
        dst[(size_t)i * VP + v] = tile[tx][ty + r];
    }
}

__global__ void k_build_wct(const float* __restrict__ wih, const float* __restrict__ whh,
                            float* __restrict__ dst) {
    __shared__ float tile[32][33];
    int j0 = blockIdx.x * 32, i0 = blockIdx.y * 32;
    int tx = threadIdx.x, ty = threadIdx.y;
#pragma unroll
    for (int r = 0; r < 32; r += 8) {
        int j = j0 + ty + r; int i = i0 + tx;
        tile[ty + r][tx] = (i < 512) ? wih[(size_t)j * 512 + i] : whh[(size_t)j * 512 + i - 512];
    }
    __syncthreads();
#pragma unroll
    for (int r = 0; r < 32; r += 8) {
        int i = i0 + ty + r; int j = j0 + tx;
        dst[(size_t)i * 2048 + j] = tile[tx][ty + r];
    }
}

__global__ void k_mean(const float* __restrict__ iml, float* __restrict__ mean) {
    int w = threadIdx.x >> 6, lane = threadIdx.x & 63;
    int row = blockIdx.x * 4 + w;
    const float* p = iml + (size_t)row * KDIM;
    float s = p[lane] + p[lane + 64] + p[lane + 128] + ((lane < 4) ? p[lane + 192] : 0.f);
#pragma unroll
    for (int off = 32; off; off >>= 1) s += __shfl_down(s, off);
    if (lane == 0) mean[row] = s * (1.f / 196.f);
}

__global__ void k_e_alpha(const float* __restrict__ iml, const float* __restrict__ attn_w,
                          float* __restrict__ alpha) {
    int b = blockIdx.x, t = threadIdx.x;
    __shared__ float wa[512];
    wa[t] = attn_w[t]; wa[t + 256] = attn_w[t + 256];
    __syncthreads();
    float acc = 0.f;
    if (t < KDIM) {
        const float* p = iml + (size_t)b * 512 * KDIM + t;
#pragma unroll 8
        for (int h = 0; h < 512; ++h) acc += p[(size_t)h * KDIM] * wa[h];
    }
    __shared__ float red[256];
    red[t] = (t < KDIM) ? acc : -__builtin_inff();
    __syncthreads();
    for (int s = 128; s; s >>= 1) { if (t < s) red[t] = fmaxf(red[t], red[t + s]); __syncthreads(); }
    float mx = red[0];
    __syncthreads();
    float ex = (t < KDIM) ? expf(acc - mx) : 0.f;
    red[t] = ex; __syncthreads();
    for (int s = 128; s; s >>= 1) { if (t < s) red[t] += red[t + s]; __syncthreads(); }
    if (t < KDIM) alpha[b * KDIM + t] = ex / red[0];
}

__global__ void k_cs(const float* __restrict__ iml, const float* __restrict__ alpha,
                     float* __restrict__ cs) {
    int w = threadIdx.x >> 6, lane = threadIdx.x & 63;
    int row = blockIdx.x * 4 + w;
    int b = row >> 9;
    const float* p = iml + (size_t)row * KDIM;
    const float* al = alpha + b * KDIM;
    float s = p[lane] * al[lane] + p[lane + 64] * al[lane + 64] + p[lane + 128] * al[lane + 128]
            + ((lane < 4) ? p[lane + 192] * al[lane + 192] : 0.f);
#pragma unroll
    for (int off = 32; off; off >>= 1) s += __shfl_down(s, off);
    if (lane == 0) cs[row] = s;
}

__global__ void k_dense_relu(const float* __restrict__ in, const float* __restrict__ W,
                             const float* __restrict__ bias, float* __restrict__ out, int ostride) {
    int b = blockIdx.y; int j = blockIdx.x * 256 + threadIdx.x;
    __shared__ float xs[512];
    xs[threadIdx.x] = in[b * 512 + threadIdx.x];
    xs[threadIdx.x + 256] = in[b * 512 + threadIdx.x + 256];
    __syncthreads();
    float acc = bias[j];
    const float4* w4 = (const float4*)(W + (size_t)j * 512);
#pragma unroll 4
    for (int i4 = 0; i4 < 128; ++i4) {
        float4 w = w4[i4];
        float4 x = *(const float4*)&xs[i4 * 4];
        acc += w.x * x.x + w.y * x.y + w.z * x.z + w.w * x.w;
    }
    out[(size_t)b * ostride + j] = fmaxf(acc, 0.f);
}

// one-time base-logits GEMM (cs @ fcT_hi), split-K 8; grid (40,8,2)
__global__ void k_gemm_big(const float* __restrict__ A, int astride,
                           const float* __restrict__ Wt, int wn,
                           float* __restrict__ part) {
    int jb = blockIdx.x, kc = blockIdx.y, bh = blockIdx.z;
    int w = threadIdx.x >> 6, lane = threadIdx.x & 63;
    int b0 = __builtin_amdgcn_readfirstlane(bh * 32 + w * 8);
    int k0 = kc * 64;
    int j0 = jb * 256 + lane * 4;
    float4 acc[8];
#pragma unroll
    for (int b = 0; b < 8; ++b) acc[b] = make_float4(0.f, 0.f, 0.f, 0.f);
    const float* wp = Wt + (size_t)k0 * wn + j0;
    const float* xp = A + (size_t)b0 * astride + k0;
#pragma unroll 8
    for (int kk = 0; kk < 64; ++kk) {
        float4 w4 = *(const float4*)(wp + (size_t)kk * wn);
#pragma unroll
        for (int b = 0; b < 8; ++b) {
            float xv = xp[(size_t)b * astride + kk];
            acc[b].x += xv * w4.x; acc[b].y += xv * w4.y;
            acc[b].z += xv * w4.z; acc[b].w += xv * w4.w;
        }
    }
#pragma unroll
    for (int b = 0; b < 8; ++b)
        *(float4*)(part + (size_t)(kc * 64 + b0 + b) * wn + j0) = acc[b];
}

__global__ void k_base_finish(const float* __restrict__ lpart, const float* __restrict__ fc_b,
                              float* __restrict__ base, u64* __restrict__ slots) {
    int b = blockIdx.y; int v = blockIdx.x * 256 + threadIdx.x;
    if (v < V) {
        float s = fc_b[v];
#pragma unroll
        for (int c = 0; c < 8; ++c) s += lpart[(size_t)(c * 64 + b) * VP + v];
        base[(size_t)b * VP + v] = s;
    }
    if (blockIdx.x == 0 && blockIdx.y == 0) {
#pragma unroll
        for (int i = 0; i < 4; ++i) slots[threadIdx.x + i * 256] = 0ull;
    }
}

// ---------------- THE persistent decode kernel ----------------
// 512 blocks x 256 thr; 3 device barriers per step; 1 dispatch for all 30 steps.
__global__ __launch_bounds__(NT, 3) void k_persist(
        const float* __restrict__ img, const float* __restrict__ emb,
        const float* __restrict__ WcT, const float* __restrict__ fcT,
        const float* __restrict__ base, const float* __restrict__ bih,
        const float* __restrict__ bhh, float* __restrict__ hbuf,
        float* __restrict__ cbuf, float* __restrict__ gpart,
        u64* __restrict__ slots, u32* __restrict__ bar,
        float* __restrict__ out0, float* __restrict__ out1) {
    __shared__ float lds[4 * 1280];    // 20KB: P2 partials; P1 uses 4*1024 of it
    const int bid = blockIdx.x, tid = threadIdx.x;
    const int w = tid >> 6, lane = tid & 63;
    u32 mygen = 0;
    u32* bcnt = bar; u32* bgen = bar + 1;

    for (int t = 0; t < TSTEPS; ++t) {
        // ---- P1: LSTM partials. tiles: 16 jb(128j) x 8 bh(8b) x 4 kc(K256) = 512 ----
        {
            const int jb = bid & 15, bh = (bid >> 4) & 7, kc = bid >> 7;
            const int b0 = bh * 8;
            const int kg0 = kc * 256 + w * 64;    // this wave's K-chunk (64)
            const float* xp[8];
            if (kg0 < 512) {
                if (t == 0) {
#pragma unroll
                    for (int b = 0; b < 8; ++b) xp[b] = img + (size_t)(b0 + b) * 512 + kg0;
                } else {
#pragma unroll
                    for (int b = 0; b < 8; ++b) {
                        u32 idx = best_idx_of_slots(slots, b0 + b);
                        xp[b] = emb + (size_t)idx * 512 + kg0;
                    }
                }
            } else {
#pragma unroll
                for (int b = 0; b < 8; ++b) xp[b] = hbuf + (size_t)(b0 + b) * 512 + (kg0 - 512);
            }
            float2 acc[8];
#pragma unroll
            for (int b = 0; b < 8; ++b) acc[b] = make_float2(0.f, 0.f);
            const float* wp = WcT + (size_t)kg0 * 2048 + jb * 128 + lane * 2;
#pragma unroll 8
            for (int kk = 0; kk < 64; ++kk) {
                float2 wv = *(const float2*)(wp + (size_t)kk * 2048);
#pragma unroll
                for (int b = 0; b < 8; ++b) {
                    float xv = xp[b][kk];
                    acc[b].x += xv * wv.x; acc[b].y += xv * wv.y;
                }
            }
#pragma unroll
            for (int b = 0; b < 8; ++b)
                *(float2*)&lds[w * 1024 + b * 128 + lane * 2] = acc[b];
            __syncthreads();
            // reduce 4 wave-partials -> gpart. 1024 outs, 4/thread
            {
                const int bl = tid >> 5;            // 0..7
                const int jj = (tid & 31) * 4;      // 0..124
                float4 s = make_float4(0.f, 0.f, 0.f, 0.f);
#pragma unroll
                for (int wv = 0; wv < 4; ++wv) {
                    float4 p = *(const float4*)&lds[wv * 1024 + bl * 128 + jj];
                    s.x += p.x; s.y += p.y; s.z += p.z; s.w += p.w;
                }
                *(float4*)&gpart[(size_t)(kc * 64 + b0 + bl) * 2048 + jb * 128 + jj] = s;
            }
        }
        gbar(bcnt, bgen, mygen);

        // ---- P1b: gates (+ out1[t-1], slot reset on block 0) ----
        {
            int e = bid * NT + tid;
            if (e < 32768) {
                int b = e >> 9, jj = e & 511;
                float g[4];
#pragma unroll
                for (int gg = 0; gg < 4; ++gg) {
                    int j = jj + gg * 512;
                    float s = bih[j] + bhh[j];
#pragma unroll
                    for (int kc = 0; kc < 4; ++kc) s += gpart[(size_t)(kc * 64 + b) * 2048 + j];
                    g[gg] = s;
                }
                float ig = 1.f / (1.f + expf(-g[0]));
                float fg = 1.f / (1.f + expf(-g[1]));
                float gt = tanhf(g[2]);
                float og = 1.f / (1.f + expf(-g[3]));
                float c = fg * cbuf[e] + ig * gt;
                float h = og * tanhf(c);
                cbuf[e] = c; hbuf[e] = h;
            }
            if (bid == 0) {
                if (t > 0 && tid < 64)
                    out1[tid * TSTEPS + (t - 1)] = (float)best_idx_of_slots(slots, tid);
                __syncthreads();
                for (int i = tid; i < B * SLOTSTRIDE; i += NT) slots[i] = 0ull;
            }
        }
        gbar(bcnt, bgen, mygen);

        // ---- P2: logits full-K fused. tiles: 64 jb(160j) x 8 bh(8b) = 512 ----
        {
            const int jb = bid & 63, bh = bid >> 6;
            const int b0 = bh * 8;
            const int kg0 = w * 128;               // wave K-chunk (128) of 512
            float2 a2[8]; float a1[8];
#pragma unroll
            for (int b = 0; b < 8; ++b) { a2[b] = make_float2(0.f, 0.f); a1[b] = 0.f; }
            const float* wp2 = fcT + (size_t)kg0 * VP + jb * 160 + lane * 2;
            const float* wp1 = fcT + (size_t)kg0 * VP + jb * 160 + 128 + (lane & 31);
            const float* hb0 = hbuf + (size_t)b0 * 512 + kg0;
#pragma unroll 4
            for (int kk = 0; kk < 128; ++kk) {
                float2 w2 = *(const float2*)(wp2 + (size_t)kk * VP);
                float w1 = wp1[(size_t)kk * VP];
#pragma unroll
                for (int b = 0; b < 8; ++b) {
                    float xv = hb0[b * 512 + kk];
                    a2[b].x += xv * w2.x; a2[b].y += xv * w2.y; a1[b] += xv * w1;
                }
            }
#pragma unroll
            for (int b = 0; b < 8; ++b)
                *(float2*)&lds[w * 1280 + b * 160 + lane * 2] = a2[b];
            if (lane < 32) {
#pragma unroll
                for (int b = 0; b < 8; ++b) lds[w * 1280 + b * 160 + 128 + lane] = a1[b];
            }
            __syncthreads();
            // reduce + epilogue: 1280 outs, 5/thread (contiguous, same b)
            {
                const int bl = tid >> 5;              // 0..7
                const int jj0 = (tid & 31) * 5;       // 0..155
                const int bg = b0 + bl;
                const int j0 = jb * 160 + jj0;
                float m = -__builtin_inff(); int mi = 0x7fffffff;
                if (j0 < V) {                          // j0 mult of 5, V mult of 5
                    float* op = out0 + ((size_t)bg * TSTEPS + t) * V + j0;
                    const float* bp = base + (size_t)bg * VP + j0;
#pragma unroll
                    for (int i = 0; i < 5; ++i) {
                        float s = 0.f;
#pragma unroll
                        for (int wv = 0; wv < 4; ++wv) s += lds[wv * 1280 + bl * 160 + jj0 + i];
                        float val = s + bp[i];
                        op[i] = val;
                        if (val > m) { m = val; mi = j0 + i; }
                    }
                }
#pragma unroll
                for (int mk = 1; mk < 32; mk <<= 1) {
                    float ov = __shfl_xor(m, mk);
                    int oi = __shfl_xor(mi, mk);
                    if (ov > m || (ov == m && oi < mi)) { m = ov; mi = oi; }
                }
                if ((lane & 31) == 0)
                    atomicMax(&slots[bg * SLOTSTRIDE + (jb & 7)], pack_vi(m, mi));
            }
        }
        gbar(bcnt, bgen, mygen);
    }
    // final samples
    if (bid == 0 && tid < 64)
        out1[tid * TSTEPS + (TSTEPS - 1)] = (float)best_idx_of_slots(slots, tid);
}

// ---------------- launch ----------------

extern "C" void kernel_launch(void* const* d_in, const int* in_sizes, int n_in,
                              void* d_out, int out_size, void* d_ws, size_t ws_size,
                              hipStream_t stream) {
    const float* iml   = (const float*)d_in[0];
    const float* img   = (const float*)d_in[1];
    const float* m1w1  = (const float*)d_in[2];
    const float* m1b1  = (const float*)d_in[3];
    const float* m1w2  = (const float*)d_in[4];
    const float* m1b2  = (const float*)d_in[5];
    const float* m2w1  = (const float*)d_in[6];
    const float* m2b1  = (const float*)d_in[7];
    const float* m2w2  = (const float*)d_in[8];
    const float* m2b2  = (const float*)d_in[9];
    const float* wih   = (const float*)d_in[10];
    const float* whh   = (const float*)d_in[11];
    const float* bih   = (const float*)d_in[12];
    const float* bhh   = (const float*)d_in[13];
    const float* attnw = (const float*)d_in[14];
    const float* fcw   = (const float*)d_in[16];
    const float* fcb   = (const float*)d_in[17];
    const float* emb   = (const float*)d_in[18];

    float* out0 = (float*)d_out;
    float* out1 = out0 + (size_t)B * TSTEPS * V;

    float* ws = (float*)d_ws;
    size_t off = 0;
    float* fcT   = ws + off; off += (size_t)512 * VP;
    float* WcT   = ws + off; off += (size_t)1024 * 2048;
    float* bigp  = ws + off; off += (size_t)8 * B * VP;      // base-path partials
    float* gpart = ws + off; off += (size_t)4 * B * 2048;    // lstm partials (4 kc)
    float* base  = ws + off; off += (size_t)B * VP;
    float* meanb = ws + off; off += B * 512;
    float* alpha = ws + off; off += B * KDIM;
    float* csb   = ws + off; off += B * 512;
    float* tmpb  = ws + off; off += B * 512;
    float* hbuf  = ws + off; off += B * 512;
    float* cbuf  = ws + off; off += B * 512;
    u64*   slots = (u64*)(ws + off); off += B * SLOTSTRIDE * 2;
    u32*   bar   = (u32*)(ws + off); off += 64;

    hipMemsetAsync(bar, 0, 2 * sizeof(u32), stream);

    // ---- precompute ----
    k_mean<<<dim3(8192), dim3(256), 0, stream>>>(iml, meanb);
    k_e_alpha<<<dim3(64), dim3(256), 0, stream>>>(iml, attnw, alpha);
    k_cs<<<dim3(8192), dim3(256), 0, stream>>>(iml, alpha, csb);
    k_dense_relu<<<dim3(2, 64), dim3(256), 0, stream>>>(meanb, m1w1, m1b1, tmpb, 512);
    k_dense_relu<<<dim3(2, 64), dim3(256), 0, stream>>>(tmpb, m1w2, m1b2, hbuf, 512);   // h0
    k_dense_relu<<<dim3(2, 64), dim3(256), 0, stream>>>(meanb, m2w1, m2b1, tmpb, 512);
    k_dense_relu<<<dim3(2, 64), dim3(256), 0, stream>>>(tmpb, m2w2, m2b2, cbuf, 512);   // c0

    k_transpose_fc<<<dim3(VP / 32, 16), dim3(32, 8), 0, stream>>>(fcw, fcT, 512);
    k_gemm_big<<<dim3(40, 8, 2), dim3(256), 0, stream>>>(csb, 512, fcT, VP, bigp);
    k_base_finish<<<dim3(NVC, 64), dim3(256), 0, stream>>>(bigp, fcb, base, slots);
    k_transpose_fc<<<dim3(VP / 32, 16), dim3(32, 8), 0, stream>>>(fcw, fcT, 0);
    k_build_wct<<<dim3(64, 32), dim3(32, 8), 0, stream>>>(wih, whh, WcT);

    // ---- entire decode loop: ONE dispatch ----
    k_persist<<<dim3(NBLK), dim3(NT), 0, stream>>>(img, emb, WcT, fcT, base, bih, bhh,
                                                   hbuf, cbuf, gpart, slots, bar, out0, out1);
}

// Round 9
// 1342.269 us; speedup vs baseline: 6.0706x; 6.0706x over previous
//
#include <hip/hip_runtime.h>
#include <hip/hip_bf16.h>

#define B 64
#define KDIM 196
#define H 512
#define V 10000
#define TSTEPS 30
#define VP 10240       // padded V: 64 strips * 160
#define NVC 40         // VP/256 chunks (base finish)
#define NSLOT 8
#define SLOTSTRIDE 16  // u64 per b -> 128B
#define NT 256

typedef unsigned long long u64;
typedef unsigned int u32;

__device__ __forceinline__ u64 pack_vi(float v, int idx) {
    u32 kb = __float_as_uint(v);
    kb = (kb & 0x80000000u) ? ~kb : (kb | 0x80000000u);
    return ((u64)kb << 32) | (u32)(~(u32)idx);
}
__device__ __forceinline__ u32 best_idx_of_slots(const u64* __restrict__ slots, int b) {
    u64 best = slots[b * SLOTSTRIDE];
#pragma unroll
    for (int s = 1; s < NSLOT; ++s) { u64 v = slots[b * SLOTSTRIDE + s]; if (v > best) best = v; }
    return ~(u32)best;
}

// ---------------- precompute kernels ----------------

// dst[i][v] = fc_w[v][coloff + i], i in [0,512), v in [0,VP) (zero-padded)
__global__ void k_transpose_fc(const float* __restrict__ fcw, float* __restrict__ dst, int coloff) {
    __shared__ float tile[32][33];
    int v0 = blockIdx.x * 32, i0 = blockIdx.y * 32;
    int tx = threadIdx.x, ty = threadIdx.y;
#pragma unroll
    for (int r = 0; r < 32; r += 8) {
        int v = v0 + ty + r; int i = i0 + tx;
        tile[ty + r][tx] = (v < V) ? fcw[(size_t)v * 1024 + coloff + i] : 0.f;
    }
    __syncthreads();
#pragma unroll
    for (int r = 0; r < 32; r += 8) {
        int i = i0 + ty + r; int v = v0 + tx;
        dst[(size_t)i * VP + v] = tile[tx][ty + r];
    }
}

// WcT[i][j] = (i<512) ? wih[j][i] : whh[j][i-512];  i<1024, j<2048
__global__ void k_build_wct(const float* __restrict__ wih, const float* __restrict__ whh,
                            float* __restrict__ dst) {
    __shared__ float tile[32][33];
    int j0 = blockIdx.x * 32, i0 = blockIdx.y * 32;
    int tx = threadIdx.x, ty = threadIdx.y;
#pragma unroll
    for (int r = 0; r < 32; r += 8) {
        int j = j0 + ty + r; int i = i0 + tx;
        tile[ty + r][tx] = (i < 512) ? wih[(size_t)j * 512 + i] : whh[(size_t)j * 512 + i - 512];
    }
    __syncthreads();
#pragma unroll
    for (int r = 0; r < 32; r += 8) {
        int i = i0 + ty + r; int j = j0 + tx;
        dst[(size_t)i * 2048 + j] = tile[tx][ty + r];
    }
}

// alpha[b][k] = softmax_k( sum_h iml[b][h][k] * attn_w[h] )
__global__ void k_e_alpha(const float* __restrict__ iml, const float* __restrict__ attn_w,
                          float* __restrict__ alpha) {
    int b = blockIdx.x, t = threadIdx.x;
    __shared__ float wa[512];
    wa[t] = attn_w[t]; wa[t + 256] = attn_w[t + 256];
    __syncthreads();
    float acc = 0.f;
    if (t < KDIM) {
        const float* p = iml + (size_t)b * 512 * KDIM + t;
#pragma unroll 8
        for (int h = 0; h < 512; ++h) acc += p[(size_t)h * KDIM] * wa[h];
    }
    __shared__ float red[256];
    red[t] = (t < KDIM) ? acc : -__builtin_inff();
    __syncthreads();
    for (int s = 128; s; s >>= 1) { if (t < s) red[t] = fmaxf(red[t], red[t + s]); __syncthreads(); }
    float mx = red[0];
    __syncthreads();
    float ex = (t < KDIM) ? expf(acc - mx) : 0.f;
    red[t] = ex; __syncthreads();
    for (int s = 128; s; s >>= 1) { if (t < s) red[t] += red[t + s]; __syncthreads(); }
    if (t < KDIM) alpha[b * KDIM + t] = ex / red[0];
}

// fused: mean[row] and cs[row] in ONE pass over iml. one wave per row.
__global__ void k_mean_cs(const float* __restrict__ iml, const float* __restrict__ alpha,
                          float* __restrict__ mean, float* __restrict__ cs) {
    int w = threadIdx.x >> 6, lane = threadIdx.x & 63;
    int row = blockIdx.x * 4 + w;
    int b = row >> 9;
    const float* p = iml + (size_t)row * KDIM;
    const float* al = alpha + b * KDIM;
    float p0 = p[lane], p1 = p[lane + 64], p2 = p[lane + 128];
    float p3 = (lane < 4) ? p[lane + 192] : 0.f;
    float a3 = (lane < 4) ? al[lane + 192] : 0.f;
    float sm = p0 + p1 + p2 + p3;
    float sc = p0 * al[lane] + p1 * al[lane + 64] + p2 * al[lane + 128] + p3 * a3;
#pragma unroll
    for (int off = 32; off; off >>= 1) { sm += __shfl_down(sm, off); sc += __shfl_down(sc, off); }
    if (lane == 0) { mean[row] = sm * (1.f / 196.f); cs[row] = sc; }
}

// dual dense+relu: z picks (in, W, bias, out). grid (2, 64, 2)
__global__ void k_dense_relu2(const float* __restrict__ in0, const float* __restrict__ in1,
                              const float* __restrict__ W0, const float* __restrict__ W1,
                              const float* __restrict__ bi0, const float* __restrict__ bi1,
                              float* __restrict__ o0, float* __restrict__ o1) {
    int z = blockIdx.z;
    const float* in = z ? in1 : in0;
    const float* W  = z ? W1 : W0;
    const float* bias = z ? bi1 : bi0;
    float* out = z ? o1 : o0;
    int b = blockIdx.y; int j = blockIdx.x * 256 + threadIdx.x;
    __shared__ float xs[512];
    xs[threadIdx.x] = in[b * 512 + threadIdx.x];
    xs[threadIdx.x + 256] = in[b * 512 + threadIdx.x + 256];
    __syncthreads();
    float acc = bias[j];
    const float4* w4 = (const float4*)(W + (size_t)j * 512);
#pragma unroll 4
    for (int i4 = 0; i4 < 128; ++i4) {
        float4 w = w4[i4];
        float4 x = *(const float4*)&xs[i4 * 4];
        acc += w.x * x.x + w.y * x.y + w.z * x.z + w.w * x.w;
    }
    out[(size_t)b * 512 + j] = fmaxf(acc, 0.f);
}

// one-time base-logits GEMM (cs @ fcT_hi), split-K 8; grid (40,8,2)
__global__ void k_gemm_big(const float* __restrict__ A, int astride,
                           const float* __restrict__ Wt, int wn,
                           float* __restrict__ part) {
    int jb = blockIdx.x, kc = blockIdx.y, bh = blockIdx.z;
    int w = threadIdx.x >> 6, lane = threadIdx.x & 63;
    int b0 = __builtin_amdgcn_readfirstlane(bh * 32 + w * 8);
    int k0 = kc * 64;
    int j0 = jb * 256 + lane * 4;
    float4 acc[8];
#pragma unroll
    for (int b = 0; b < 8; ++b) acc[b] = make_float4(0.f, 0.f, 0.f, 0.f);
    const float* wp = Wt + (size_t)k0 * wn + j0;
    const float* xp = A + (size_t)b0 * astride + k0;
#pragma unroll 8
    for (int kk = 0; kk < 64; ++kk) {
        float4 w4 = *(const float4*)(wp + (size_t)kk * wn);
#pragma unroll
        for (int b = 0; b < 8; ++b) {
            float xv = xp[(size_t)b * astride + kk];
            acc[b].x += xv * w4.x; acc[b].y += xv * w4.y;
            acc[b].z += xv * w4.z; acc[b].w += xv * w4.w;
        }
    }
#pragma unroll
    for (int b = 0; b < 8; ++b)
        *(float4*)(part + (size_t)(kc * 64 + b0 + b) * wn + j0) = acc[b];
}

__global__ void k_base_finish(const float* __restrict__ lpart, const float* __restrict__ fc_b,
                              float* __restrict__ base, u64* __restrict__ slots) {
    int b = blockIdx.y; int v = blockIdx.x * 256 + threadIdx.x;
    if (v < V) {
        float s = fc_b[v];
#pragma unroll
        for (int c = 0; c < 8; ++c) s += lpart[(size_t)(c * 64 + b) * VP + v];
        base[(size_t)b * VP + v] = s;
    }
    if (blockIdx.x == 0 && blockIdx.y == 0) {
#pragma unroll
        for (int i = 0; i < 4; ++i) slots[threadIdx.x + i * 256] = 0ull;
    }
}

// ---------------- per-step kernels (bodies validated in r8's persistent kernel) ----------------

// LSTM partials: grid (16 jb x 4 kc x 8 bh) = 512 blocks; wave = 8b x 128j x K64;
// 4 waves cover K=256 per block, LDS-reduced -> gpart[kc partials]
__global__ __launch_bounds__(NT) void k_lstm(
        const float* __restrict__ img, const float* __restrict__ emb,
        const u64* __restrict__ slots, const float* __restrict__ hbuf,
        const float* __restrict__ WcT, float* __restrict__ gpart, int t0) {
    __shared__ float lds[4 * 1024];
    const int jb = blockIdx.x, kc = blockIdx.y, bh = blockIdx.z;
    const int tid = threadIdx.x;
    const int w = __builtin_amdgcn_readfirstlane(tid >> 6), lane = tid & 63;
    const int b0 = bh * 8;
    const int kg0 = kc * 256 + w * 64;
    const float* xp[8];
    if (kg0 < 512) {
        if (t0) {
#pragma unroll
            for (int b = 0; b < 8; ++b) xp[b] = img + (size_t)(b0 + b) * 512 + kg0;
        } else {
#pragma unroll
            for (int b = 0; b < 8; ++b) {
                u32 idx = best_idx_of_slots(slots, b0 + b);
                xp[b] = emb + (size_t)idx * 512 + kg0;
            }
        }
    } else {
#pragma unroll
        for (int b = 0; b < 8; ++b) xp[b] = hbuf + (size_t)(b0 + b) * 512 + (kg0 - 512);
    }
    float2 acc[8];
#pragma unroll
    for (int b = 0; b < 8; ++b) acc[b] = make_float2(0.f, 0.f);
    const float* wp = WcT + (size_t)kg0 * 2048 + jb * 128 + lane * 2;
#pragma unroll 8
    for (int kk = 0; kk < 64; ++kk) {
        float2 wv = *(const float2*)(wp + (size_t)kk * 2048);
#pragma unroll
        for (int b = 0; b < 8; ++b) {
            float xv = xp[b][kk];
            acc[b].x += xv * wv.x; acc[b].y += xv * wv.y;
        }
    }
#pragma unroll
    for (int b = 0; b < 8; ++b)
        *(float2*)&lds[w * 1024 + b * 128 + lane * 2] = acc[b];
    __syncthreads();
    {
        const int bl = tid >> 5;            // 0..7
        const int jj = (tid & 31) * 4;      // 0..124
        float4 s = make_float4(0.f, 0.f, 0.f, 0.f);
#pragma unroll
        for (int wv = 0; wv < 4; ++wv) {
            float4 p = *(const float4*)&lds[wv * 1024 + bl * 128 + jj];
            s.x += p.x; s.y += p.y; s.z += p.z; s.w += p.w;
        }
        *(float4*)&gpart[(size_t)(kc * 64 + b0 + bl) * 2048 + jb * 128 + jj] = s;
    }
}

// gates: reduce 4 partials + biases; h -> hbuf, c in place.
// block 0: out1[t-1] from slots, then slot reset. grid 128 x 256.
__global__ void k_gates(const float* __restrict__ gpart, const float* __restrict__ bih,
                        const float* __restrict__ bhh, float* __restrict__ hbuf,
                        float* __restrict__ cbuf, u64* __restrict__ slots,
                        float* __restrict__ out1, int t) {
    int e = blockIdx.x * 256 + threadIdx.x;
    int b = e >> 9, jj = e & 511;
    float g[4];
#pragma unroll
    for (int gg = 0; gg < 4; ++gg) {
        int j = jj + gg * 512;
        float s = bih[j] + bhh[j];
#pragma unroll
        for (int kc = 0; kc < 4; ++kc) s += gpart[(size_t)(kc * 64 + b) * 2048 + j];
        g[gg] = s;
    }
    float ig = 1.f / (1.f + expf(-g[0]));
    float fg = 1.f / (1.f + expf(-g[1]));
    float gt = tanhf(g[2]);
    float og = 1.f / (1.f + expf(-g[3]));
    float c = fg * cbuf[e] + ig * gt;
    float h = og * tanhf(c);
    cbuf[e] = c; hbuf[e] = h;
    if (blockIdx.x == 0) {
        if (t > 0 && threadIdx.x < 64)
            out1[threadIdx.x * TSTEPS + (t - 1)] = (float)best_idx_of_slots(slots, threadIdx.x);
        __syncthreads();
        for (int i = threadIdx.x; i < B * SLOTSTRIDE; i += 256) slots[i] = 0ull;
    }
}

// logits full-K fused: grid (64 jb x 8 bh) = 512 blocks; wave = 8b x 160j x K128;
// 4 waves cover K=512, LDS-reduce, epilogue: +base, out0 write, argmax -> slots.
__global__ __launch_bounds__(NT) void k_logits_fullk(
        const float* __restrict__ hbuf, const float* __restrict__ fcT,
        const float* __restrict__ base, float* __restrict__ out0,
        u64* __restrict__ slots, int t) {
    __shared__ float lds[4 * 1280];
    const int jb = blockIdx.x, bh = blockIdx.y;
    const int tid = threadIdx.x;
    const int w = __builtin_amdgcn_readfirstlane(tid >> 6), lane = tid & 63;
    const int b0 = bh * 8;
    const int kg0 = w * 128;
    float2 a2[8]; float a1[8];
#pragma unroll
    for (int b = 0; b < 8; ++b) { a2[b] = make_float2(0.f, 0.f); a1[b] = 0.f; }
    const float* wp2 = fcT + (size_t)kg0 * VP + jb * 160 + lane * 2;
    const float* wp1 = fcT + (size_t)kg0 * VP + jb * 160 + 128 + (lane & 31);
    const float* hb0 = hbuf + (size_t)b0 * 512 + kg0;
#pragma unroll 4
    for (int kk = 0; kk < 128; ++kk) {
        float2 w2 = *(const float2*)(wp2 + (size_t)kk * VP);
        float w1 = wp1[(size_t)kk * VP];
#pragma unroll
        for (int b = 0; b < 8; ++b) {
            float xv = hb0[b * 512 + kk];
            a2[b].x += xv * w2.x; a2[b].y += xv * w2.y; a1[b] += xv * w1;
        }
    }
#pragma unroll
    for (int b = 0; b < 8; ++b)
        *(float2*)&lds[w * 1280 + b * 160 + lane * 2] = a2[b];
    if (lane < 32) {
#pragma unroll
        for (int b = 0; b < 8; ++b) lds[w * 1280 + b * 160 + 128 + lane] = a1[b];
    }
    __syncthreads();
    {
        const int bl = tid >> 5;              // 0..7
        const int jj0 = (tid & 31) * 5;       // 0..155
        const int bg = b0 + bl;
        const int j0 = jb * 160 + jj0;
        float m = -__builtin_inff(); int mi = 0x7fffffff;
        if (j0 < V) {                          // j0, V multiples of 5
            float* op = out0 + ((size_t)bg * TSTEPS + t) * V + j0;
            const float* bp = base + (size_t)bg * VP + j0;
#pragma unroll
            for (int i = 0; i < 5; ++i) {
                float s = 0.f;
#pragma unroll
                for (int wv = 0; wv < 4; ++wv) s += lds[wv * 1280 + bl * 160 + jj0 + i];
                float val = s + bp[i];
                op[i] = val;
                if (val > m) { m = val; mi = j0 + i; }
            }
        }
#pragma unroll
        for (int mk = 1; mk < 32; mk <<= 1) {
            float ov = __shfl_xor(m, mk);
            int oi = __shfl_xor(mi, mk);
            if (ov > m || (ov == m && oi < mi)) { m = ov; mi = oi; }
        }
        if ((lane & 31) == 0)
            atomicMax(&slots[bg * SLOTSTRIDE + (jb & 7)], pack_vi(m, mi));
    }
}

__global__ void k_final_out1(const u64* __restrict__ slots, float* __restrict__ out1) {
    int b = threadIdx.x;
    if (b < B) out1[b * TSTEPS + (TSTEPS - 1)] = (float)best_idx_of_slots(slots, b);
}

// ---------------- launch ----------------

extern "C" void kernel_launch(void* const* d_in, const int* in_sizes, int n_in,
                              void* d_out, int out_size, void* d_ws, size_t ws_size,
                              hipStream_t stream) {
    const float* iml   = (const float*)d_in[0];
    const float* img   = (const float*)d_in[1];
    const float* m1w1  = (const float*)d_in[2];
    const float* m1b1  = (const float*)d_in[3];
    const float* m1w2  = (const float*)d_in[4];
    const float* m1b2  = (const float*)d_in[5];
    const float* m2w1  = (const float*)d_in[6];
    const float* m2b1  = (const float*)d_in[7];
    const float* m2w2  = (const float*)d_in[8];
    const float* m2b2  = (const float*)d_in[9];
    const float* wih   = (const float*)d_in[10];
    const float* whh   = (const float*)d_in[11];
    const float* bih   = (const float*)d_in[12];
    const float* bhh   = (const float*)d_in[13];
    const float* attnw = (const float*)d_in[14];
    const float* fcw   = (const float*)d_in[16];
    const float* fcb   = (const float*)d_in[17];
    const float* emb   = (const float*)d_in[18];

    float* out0 = (float*)d_out;
    float* out1 = out0 + (size_t)B * TSTEPS * V;

    float* ws = (float*)d_ws;
    size_t off = 0;
    float* fcT   = ws + off; off += (size_t)512 * VP;        // 21MB (hi then lo, overwritten)
    float* WcT   = ws + off; off += (size_t)1024 * 2048;     // 8.4MB
    float* bigp  = ws + off; off += (size_t)8 * B * VP;      // 21MB base-path partials
    float* gpart = ws + off; off += (size_t)4 * B * 2048;    // 2.1MB lstm partials
    float* base  = ws + off; off += (size_t)B * VP;          // 2.6MB
    float* meanb = ws + off; off += B * 512;
    float* alpha = ws + off; off += B * KDIM;
    float* csb   = ws + off; off += B * 512;
    float* tmp1  = ws + off; off += B * 512;
    float* tmp2  = ws + off; off += B * 512;
    float* hbuf  = ws + off; off += B * 512;
    float* cbuf  = ws + off; off += B * 512;
    u64*   slots = (u64*)(ws + off); off += B * SLOTSTRIDE * 2;

    // ---- precompute (9 dispatches) ----
    k_e_alpha<<<dim3(64), dim3(256), 0, stream>>>(iml, attnw, alpha);
    k_mean_cs<<<dim3(8192), dim3(256), 0, stream>>>(iml, alpha, meanb, csb);
    k_dense_relu2<<<dim3(2, 64, 2), dim3(256), 0, stream>>>(meanb, meanb, m1w1, m2w1, m1b1, m2b1, tmp1, tmp2);
    k_dense_relu2<<<dim3(2, 64, 2), dim3(256), 0, stream>>>(tmp1, tmp2, m1w2, m2w2, m1b2, m2b2, hbuf, cbuf);
    k_transpose_fc<<<dim3(VP / 32, 16), dim3(32, 8), 0, stream>>>(fcw, fcT, 512);   // hi half
    k_gemm_big<<<dim3(40, 8, 2), dim3(256), 0, stream>>>(csb, 512, fcT, VP, bigp);
    k_base_finish<<<dim3(NVC, 64), dim3(256), 0, stream>>>(bigp, fcb, base, slots);
    k_transpose_fc<<<dim3(VP / 32, 16), dim3(32, 8), 0, stream>>>(fcw, fcT, 0);     // lo half (step loop)
    k_build_wct<<<dim3(64, 32), dim3(32, 8), 0, stream>>>(wih, whh, WcT);

    // ---- decode loop: 3 kernels/step ----
    for (int t = 0; t < TSTEPS; ++t) {
        k_lstm<<<dim3(16, 4, 8), dim3(NT), 0, stream>>>(img, emb, slots, hbuf, WcT, gpart, (t == 0) ? 1 : 0);
        k_gates<<<dim3(128), dim3(256), 0, stream>>>(gpart, bih, bhh, hbuf, cbuf, slots, out1, t);
        k_logits_fullk<<<dim3(64, 8), dim3(NT), 0, stream>>>(hbuf, fcT, base, out0, slots, t);
    }
    k_final_out1<<<dim3(1), dim3(64), 0, stream>>>(slots, out1);
}